// Round 15
// baseline (11263.797 us; speedup 1.0000x reference)
//
#include <hip/hip_runtime.h>
#include <hip/hip_bf16.h>
#include <hip/hip_fp16.h>
#include <math.h>

#define Q_N 4096
#define M_N 65536
#define D_N 1024
#define TOPK 8
#define SEGS 32
#define KPS (M_N / SEGS)       // 2048 keys per segment
#define CANDS (SEGS * TOPK)    // 256 candidates per query
#define NRES 32                // rescored candidates per query

// MFMA tile params: block = 256 queries x 128 keys/step, 4 waves,
// wave = 128 keys x 64 queries (fm=8, fn=4 -> 32 MFMA / 12 ds_read = 2.67)
#define BMQ 256                // queries per block
#define BNK 128                // keys per step tile
#define BK 32
#define NSUB (KPS / BNK)       // 16 subtiles per segment
#define NKT (D_N / BK)         // 32 K-steps per subtile
#define NSTEP (NSUB * NKT)     // 512 pipeline steps per segment
#define QTILES (Q_N / BMQ)     // 16 query tiles

typedef short s16x8 __attribute__((ext_vector_type(8)));
typedef float f32x4 __attribute__((ext_vector_type(4)));

__device__ __forceinline__ bool better(float v0, int i0, float v1, int i1) {
  return (v0 > v1) || (v0 == v1 && i0 < i1);
}

__device__ __forceinline__ unsigned short f2bf(float f) {
  union { __hip_bfloat16 h; unsigned short u; } c;
  c.h = __float2bfloat16(f);
  return c.u;
}

// async global->LDS, 16B per lane; lds base wave-uniform, dest linear (lane*16)
__device__ __forceinline__ void gll16(void* lds, const void* g) {
  __builtin_amdgcn_global_load_lds(
      (const __attribute__((address_space(1))) unsigned int*)(uintptr_t)g,
      (__attribute__((address_space(3))) unsigned int*)(uintptr_t)lds, 16, 0, 0);
}

// ---------------- K1: key norms + normalized bf16 conversion ----------------
__global__ __launch_bounds__(256) void knorm_scale_kernel(const float* __restrict__ keys,
                                                          unsigned short* __restrict__ kb,
                                                          float* __restrict__ rnk) {
  int row = blockIdx.x;
  int tid = threadIdx.x;
  float4 v = reinterpret_cast<const float4*>(keys + (size_t)row * D_N)[tid];
  float s = v.x * v.x + v.y * v.y + v.z * v.z + v.w * v.w;
#pragma unroll
  for (int off = 32; off > 0; off >>= 1) s += __shfl_down(s, off);
  __shared__ float part[4];
  __shared__ float rs;
  int lane = tid & 63, wid = tid >> 6;
  if (lane == 0) part[wid] = s;
  __syncthreads();
  if (tid == 0) {
    float t = part[0] + part[1] + part[2] + part[3];
    rs = 1.0f / fmaxf(sqrtf(t), 1e-12f);
  }
  __syncthreads();
  float r = rs;
  ushort4 o;
  o.x = f2bf(v.x * r); o.y = f2bf(v.y * r); o.z = f2bf(v.z * r); o.w = f2bf(v.w * r);
  reinterpret_cast<ushort4*>(kb + (size_t)row * D_N)[tid] = o;
  if (tid == 0) rnk[row] = r;
}

// ---------------- K2: query norms -> fp32 (rescore) + bf16 (MFMA) ----------
__global__ __launch_bounds__(256) void qnorm_dual_kernel(const float* __restrict__ q,
                                                         float* __restrict__ qn,
                                                         unsigned short* __restrict__ qb) {
  int row = blockIdx.x;
  int tid = threadIdx.x;
  float4 v = reinterpret_cast<const float4*>(q + (size_t)row * D_N)[tid];
  float s = v.x * v.x + v.y * v.y + v.z * v.z + v.w * v.w;
#pragma unroll
  for (int off = 32; off > 0; off >>= 1) s += __shfl_down(s, off);
  __shared__ float part[4];
  __shared__ float rs;
  int lane = tid & 63, wid = tid >> 6;
  if (lane == 0) part[wid] = s;
  __syncthreads();
  if (tid == 0) {
    float t = part[0] + part[1] + part[2] + part[3];
    rs = 1.0f / fmaxf(sqrtf(t), 1e-12f);
  }
  __syncthreads();
  float r = rs;
  float4 o;
  o.x = v.x * r; o.y = v.y * r; o.z = v.z * r; o.w = v.w * r;
  reinterpret_cast<float4*>(qn + (size_t)row * D_N)[tid] = o;
  ushort4 ob;
  ob.x = f2bf(o.x); ob.y = f2bf(o.y); ob.z = f2bf(o.z); ob.w = f2bf(o.w);
  reinterpret_cast<ushort4*>(qb + (size_t)row * D_N)[tid] = ob;
}

// ---------------- K3: bf16 MFMA sims + in-register per-segment top-8 --------
// Geometry change targeting LDS-BW/MFMA: wave = 128k x 64q (acc 8x4),
// 32 MFMA per 12 ds_read_b128. Ring-3 LDS (72 KB -> 2 blocks/CU), ONE raw
// barrier/step, counted vmcnt(6), R5 involutive swizzle, R11-style
// cache-partitioned mapping (XCD pair owns 4 qtiles = 2MB L2-resident A),
// R14 screened fold. Swapped operands: mfma(keyfrag, queryfrag).
__global__ __launch_bounds__(256, 2) void simsb_kernel(const unsigned short* __restrict__ qb,
                                                       const unsigned short* __restrict__ kb,
                                                       float* __restrict__ cand_val,
                                                       int* __restrict__ cand_idx) {
  __shared__ __align__(16) union SmemU {
    struct {
      unsigned short A[3][BMQ * BK];  // 3 x 16 KB queries
      unsigned short B[3][BNK * BK];  // 3 x 8 KB keys
    } ab;                             // 72 KB
    struct {
      float v[BMQ * 4 * TOPK];        // 32 KB: per-query 4 lane-group lists
      int i[BMQ * 4 * TOPK];          // 32 KB
    } mg;
  } smem;

  const int tid = threadIdx.x;
  const int lane = tid & 63;
  const int wid = tid >> 6;          // 0..3

  // cache-partitioned mapping: x = XCD, idx in-XCD (0..63).
  // qtile = (x>>1)*4 + (idx&3)  (4 qtiles per XCD pair -> 2MB A-slice per XCD)
  // seg   = (x&1)*16 + (idx>>2) (bijective over 16 qtiles x 32 segs = 512)
  const int orig = blockIdx.x;
  const int x = orig & 7;
  const int idx = orig >> 3;
  const int qtile = ((x >> 1) << 2) + (idx & 3);
  const int seg = ((x & 1) << 4) + (idx >> 2);
  const int qbase = qtile * BMQ;
  const int segBase = seg * KPS;

  // staging geometry (R5 swizzle): A: wave stages rows [wid*64,+64) (4 gll16);
  // B: rows [wid*32,+32) (2 gll16). Source pre-swizzled, LDS dest linear.
  const int srowA = (wid << 6) + (lane >> 2);
  const int srowB = (wid << 5) + (lane >> 2);
  const int scol = (((lane & 3) ^ ((lane >> 3) & 3)) << 3);
  const unsigned short* aSeg = qb + (size_t)(qbase + srowA) * D_N + scol;
  const unsigned short* bSeg = kb + (size_t)(segBase + srowB) * D_N + scol;

  // fragment geometry (R5): fr = row-within-16, g = k-chunk group
  const int fr = lane & 15;
  const int g = lane >> 4;
  const int chunk_phys = g ^ ((fr >> 1) & 3);
  // loop-invariant read bases (slot offset added at use: A stride 8192, B 4096)
  const unsigned short* rB = &smem.ab.B[0][0] + (fr << 5) + (chunk_phys << 3);
  const unsigned short* rA = &smem.ab.A[0][0] + (((wid << 6) + fr) << 5) + (chunk_phys << 3);

  // per-lane running top-8 for 4 queries (q = qbase + wid*64 + n*16 + fr),
  // over this lane's key partition (keys m*16 + g*4 + j; m = 0..7)
  float lv[4][TOPK];
  int li[4][TOPK];
#pragma unroll
  for (int n = 0; n < 4; ++n)
#pragma unroll
    for (int j = 0; j < TOPK; ++j) { lv[n][j] = -1e30f; li[n][j] = 0x7fffffff; }

  f32x4 acc[8][4];   // [m key-frag][n query-frag] = 128 VGPR
#pragma unroll
  for (int m = 0; m < 8; ++m)
#pragma unroll
    for (int n = 0; n < 4; ++n) acc[m][n] = (f32x4)0.0f;

  // prologue: stage steps 0,1 into slots 0,1 (6 gll16/wave each)
#pragma unroll
  for (int p = 0; p < 2; ++p) {
    const unsigned short* aS = aSeg + (p << 5);
    const unsigned short* bS = bSeg + (p << 5);
#pragma unroll
    for (int i = 0; i < 4; ++i)
      gll16(&smem.ab.A[p][0] + (wid << 11) + (i << 9), aS + (size_t)(i << 4) * D_N);
#pragma unroll
    for (int i = 0; i < 2; ++i)
      gll16(&smem.ab.B[p][0] + (wid << 10) + (i << 9), bS + (size_t)(i << 4) * D_N);
  }

  int cur = 0;   // ring slot
#pragma unroll 1
  for (int v = 0; v < NSTEP; ++v) {
    // wait for own step's 6 loads, leave next step's 6 in flight
    if (v < NSTEP - 1) {
      asm volatile("s_waitcnt vmcnt(6)" ::: "memory");
    } else {
      asm volatile("s_waitcnt vmcnt(0)" ::: "memory");
    }
    __builtin_amdgcn_sched_barrier(0);
    __builtin_amdgcn_s_barrier();   // single barrier per step
    __builtin_amdgcn_sched_barrier(0);

    // restage step v+2 into slot (cur+2)%3 (its readers finished at v-1:
    // their MFMAs consumed the reads before reaching this barrier)
    if (v + 2 < NSTEP) {
      const int v2 = v + 2;
      int nxt = cur + 2; if (nxt >= 3) nxt -= 3;
      const unsigned short* aS = aSeg + ((v2 & 31) << 5);
      const unsigned short* bS = bSeg + ((size_t)(v2 >> 5) * BNK) * D_N + ((v2 & 31) << 5);
#pragma unroll
      for (int i = 0; i < 4; ++i)
        gll16(&smem.ab.A[nxt][0] + (wid << 11) + (i << 9), aS + (size_t)(i << 4) * D_N);
#pragma unroll
      for (int i = 0; i < 2; ++i)
        gll16(&smem.ab.B[nxt][0] + (wid << 10) + (i << 9), bS + (size_t)(i << 4) * D_N);
    }

    // fragment reads + MFMA in two m-halves (bounds frag live range)
    const unsigned short* Acur = rA + cur * (BMQ * BK);
    const unsigned short* Bcur = rB + cur * (BNK * BK);
    s16x8 bq[4];
#pragma unroll
    for (int n = 0; n < 4; ++n) bq[n] = *(const s16x8*)(Acur + (n << 9));

    __builtin_amdgcn_s_setprio(1);
    {
      s16x8 af0[4];
#pragma unroll
      for (int m = 0; m < 4; ++m) af0[m] = *(const s16x8*)(Bcur + (m << 9));
#pragma unroll
      for (int m = 0; m < 4; ++m)
#pragma unroll
        for (int n = 0; n < 4; ++n)
          acc[m][n] = __builtin_amdgcn_mfma_f32_16x16x32_bf16(af0[m], bq[n], acc[m][n], 0, 0, 0);
    }
    {
      s16x8 af1[4];
#pragma unroll
      for (int m = 0; m < 4; ++m) af1[m] = *(const s16x8*)(Bcur + ((m + 4) << 9));
#pragma unroll
      for (int m = 0; m < 4; ++m)
#pragma unroll
        for (int n = 0; n < 4; ++n)
          acc[m + 4][n] = __builtin_amdgcn_mfma_f32_16x16x32_bf16(af1[m], bq[n], acc[m + 4][n], 0, 0, 0);
    }
    __builtin_amdgcn_s_setprio(0);

    // subtile boundary: screened fold into per-lane top-8, reset acc
    if ((v & (NKT - 1)) == NKT - 1) {
      const int kb0 = segBase + ((v >> 5) << 7) + (g << 2);
#pragma unroll
      for (int n = 0; n < 4; ++n)
#pragma unroll
        for (int m = 0; m < 8; ++m) {
          float q0 = acc[m][n][0], q1 = acc[m][n][1];
          float q2 = acc[m][n][2], q3 = acc[m][n][3];
          acc[m][n] = (f32x4)0.0f;
          float mx = fmaxf(fmaxf(q0, q1), fmaxf(q2, q3));
          const int id0 = kb0 + (m << 4);
          if (better(mx, id0, lv[n][TOPK - 1], li[n][TOPK - 1])) {
            float vals[4] = {q0, q1, q2, q3};
#pragma unroll
            for (int j = 0; j < 4; ++j) {
              float val = vals[j];
              int id = id0 + j;
              if (better(val, id, lv[n][TOPK - 1], li[n][TOPK - 1])) {
                float cv = val; int ci = id;
#pragma unroll
                for (int p = 0; p < TOPK; ++p) {
                  if (better(cv, ci, lv[n][p], li[n][p])) {
                    float tv = lv[n][p]; int ti = li[n][p];
                    lv[n][p] = cv; li[n][p] = ci;
                    cv = tv; ci = ti;
                  }
                }
              }
            }
          }
        }
    }

    ++cur; if (cur == 3) cur = 0;
  }

  __syncthreads();   // all LDS frag reads done before overlaying mg scratch

  // dump per-lane lists: query-local ql = wid*64 + n*16 + fr, group g
#pragma unroll
  for (int n = 0; n < 4; ++n) {
    const int ql = (wid << 6) + (n << 4) + fr;
#pragma unroll
    for (int j = 0; j < TOPK; ++j) {
      smem.mg.v[((ql << 2) + g) * TOPK + j] = lv[n][j];
      smem.mg.i[((ql << 2) + g) * TOPK + j] = li[n][j];
    }
  }
  __syncthreads();

  // thread per query (256 threads = 256 queries): 4-way merge -> top-8
  {
    const int rb = tid << 5;   // 4 lists x 8
    int p0 = 0, p1 = 0, p2 = 0, p3 = 0;
    size_t base = (size_t)(qbase + tid) * CANDS + seg * TOPK;
#pragma unroll
    for (int j = 0; j < TOPK; ++j) {
      float v0 = smem.mg.v[rb + 0 + p0];  int i0 = smem.mg.i[rb + 0 + p0];
      float v1 = smem.mg.v[rb + 8 + p1];  int i1 = smem.mg.i[rb + 8 + p1];
      float v2 = smem.mg.v[rb + 16 + p2]; int i2 = smem.mg.i[rb + 16 + p2];
      float v3 = smem.mg.v[rb + 24 + p3]; int i3 = smem.mg.i[rb + 24 + p3];
      float bv = v0; int bi = i0; int sel = 0;
      if (better(v1, i1, bv, bi)) { bv = v1; bi = i1; sel = 1; }
      if (better(v2, i2, bv, bi)) { bv = v2; bi = i2; sel = 2; }
      if (better(v3, i3, bv, bi)) { bv = v3; bi = i3; sel = 3; }
      cand_val[base + j] = bv;
      cand_idx[base + j] = bi;
      p0 += (sel == 0); p1 += (sel == 1); p2 += (sel == 2); p3 += (sel == 3);
    }
  }
}

// ---------------- K4: merge + exact fp32 rescore + select + gather ---------
__global__ __launch_bounds__(256) void merge_kernel(const float* __restrict__ qn,
                                                    const float* __restrict__ keys,
                                                    const float* __restrict__ values,
                                                    const float* __restrict__ rnk,
                                                    const float* __restrict__ cand_val,
                                                    const int* __restrict__ cand_idx,
                                                    float* __restrict__ out) {
  const int q = blockIdx.x;
  const int tid = threadIdx.x;
  const int lane = tid & 63;
  const int w = tid >> 6;
  __shared__ float sv[CANDS];
  __shared__ int si[CANDS];
  sv[tid] = cand_val[(size_t)q * CANDS + tid];
  si[tid] = cand_idx[(size_t)q * CANDS + tid];
  __syncthreads();
  for (int k = 2; k <= CANDS; k <<= 1) {
    for (int j = k >> 1; j > 0; j >>= 1) {
      int ixj = tid ^ j;
      if (ixj > tid) {
        float v0 = sv[tid], v1 = sv[ixj];
        int i0 = si[tid], i1 = si[ixj];
        bool desc = ((tid & k) == 0);
        bool dosw = desc ? better(v1, i1, v0, i0) : better(v0, i0, v1, i1);
        if (dosw) { sv[tid] = v1; si[tid] = i1; sv[ixj] = v0; si[ixj] = i0; }
      }
      __syncthreads();
    }
  }
  __shared__ float rsc[NRES];
  const float* qrow = &qn[(size_t)q * D_N + lane * 16];
  float4 qv0 = *reinterpret_cast<const float4*>(qrow + 0);
  float4 qv1 = *reinterpret_cast<const float4*>(qrow + 4);
  float4 qv2 = *reinterpret_cast<const float4*>(qrow + 8);
  float4 qv3 = *reinterpret_cast<const float4*>(qrow + 12);
  for (int c = w; c < NRES; c += 4) {
    int id = si[c];
    const float* kr = &keys[(size_t)id * D_N + lane * 16];
    float4 k0 = *reinterpret_cast<const float4*>(kr + 0);
    float4 k1 = *reinterpret_cast<const float4*>(kr + 4);
    float4 k2 = *reinterpret_cast<const float4*>(kr + 8);
    float4 k3 = *reinterpret_cast<const float4*>(kr + 12);
    float s = qv0.x * k0.x + qv0.y * k0.y + qv0.z * k0.z + qv0.w * k0.w
            + qv1.x * k1.x + qv1.y * k1.y + qv1.z * k1.z + qv1.w * k1.w
            + qv2.x * k2.x + qv2.y * k2.y + qv2.z * k2.z + qv2.w * k2.w
            + qv3.x * k3.x + qv3.y * k3.y + qv3.z * k3.z + qv3.w * k3.w;
#pragma unroll
    for (int off = 32; off > 0; off >>= 1) s += __shfl_down(s, off);
    if (lane == 0) rsc[c] = s * rnk[id];
  }
  __syncthreads();
  __shared__ int sel[TOPK];
  if (tid == 0) {
    unsigned used = 0;
    for (int j = 0; j < TOPK; ++j) {
      int best = -1;
      for (int c = 0; c < NRES; ++c) {
        if ((used >> c) & 1u) continue;
        if (best < 0 || better(rsc[c], si[c], rsc[best], si[best])) best = c;
      }
      used |= 1u << best;
      sel[j] = si[best];
    }
  }
  __syncthreads();
#pragma unroll
  for (int j = 0; j < TOPK; ++j) {
    int row = sel[j];
    float4 v = *reinterpret_cast<const float4*>(&values[(size_t)row * D_N + tid * 4]);
    *reinterpret_cast<float4*>(&out[(size_t)q * (TOPK * D_N) + j * D_N + tid * 4]) = v;
  }
}

extern "C" void kernel_launch(void* const* d_in, const int* in_sizes, int n_in,
                              void* d_out, int out_size, void* d_ws, size_t ws_size,
                              hipStream_t stream) {
  const float* query  = (const float*)d_in[0];
  const float* keys   = (const float*)d_in[1];
  const float* values = (const float*)d_in[2];
  float* out = (float*)d_out;
  char* ws = (char*)d_ws;

  const size_t offQn  = 0;
  const size_t offQb  = offQn + (size_t)Q_N * D_N * 4;
  const size_t offKb  = offQb + (size_t)Q_N * D_N * 2;
  const size_t offRnk = offKb + (size_t)M_N * D_N * 2;
  const size_t offCv  = offRnk + (size_t)M_N * 4;
  const size_t offCi  = offCv + (size_t)Q_N * CANDS * 4;

  float* qn = (float*)(ws + offQn);
  unsigned short* qb = (unsigned short*)(ws + offQb);
  unsigned short* kb = (unsigned short*)(ws + offKb);
  float* rnk = (float*)(ws + offRnk);
  float* cand_val = (float*)(ws + offCv);
  int* cand_idx = (int*)(ws + offCi);

  hipLaunchKernelGGL(knorm_scale_kernel, dim3(M_N), dim3(256), 0, stream, keys, kb, rnk);
  hipLaunchKernelGGL(qnorm_dual_kernel, dim3(Q_N), dim3(256), 0, stream, query, qn, qb);
  hipLaunchKernelGGL(simsb_kernel, dim3(QTILES * SEGS), dim3(256), 0, stream,
                     qb, kb, cand_val, cand_idx);
  hipLaunchKernelGGL(merge_kernel, dim3(Q_N), dim3(256), 0, stream,
                     qn, keys, values, rnk, cand_val, cand_idx, out);
}

// Round 16
// 1124.042 us; speedup vs baseline: 10.0208x; 10.0208x over previous
//
#include <hip/hip_runtime.h>
#include <hip/hip_bf16.h>
#include <hip/hip_fp16.h>
#include <math.h>

#define Q_N 4096
#define M_N 65536
#define D_N 1024
#define TOPK 8
#define SEGS 32
#define KPS (M_N / SEGS)       // 2048 keys per segment
#define CANDS (SEGS * TOPK)    // 256 candidates per query
#define NRES 16                // rescored candidates per query (gap ~15 sigma)

// MFMA tile params (R14 diet kernel on ring-3)
#define BM 128
#define BN 128
#define BK 32
#define NSUB (KPS / BN)        // 16 subtiles per segment
#define NKT (D_N / BK)         // 32 K-steps per subtile
#define NSTEP (NSUB * NKT)     // 512 pipeline steps per segment
#define QT128 (Q_N / BM)       // 32 query tiles

typedef short s16x8 __attribute__((ext_vector_type(8)));
typedef float f32x4 __attribute__((ext_vector_type(4)));

__device__ __forceinline__ bool better(float v0, int i0, float v1, int i1) {
  return (v0 > v1) || (v0 == v1 && i0 < i1);
}

__device__ __forceinline__ unsigned short f2bf(float f) {
  union { __hip_bfloat16 h; unsigned short u; } c;
  c.h = __float2bfloat16(f);
  return c.u;
}

// async global->LDS, 16B per lane; lds base wave-uniform, dest linear (lane*16)
__device__ __forceinline__ void gll16(void* lds, const void* g) {
  __builtin_amdgcn_global_load_lds(
      (const __attribute__((address_space(1))) unsigned int*)(uintptr_t)g,
      (__attribute__((address_space(3))) unsigned int*)(uintptr_t)lds, 16, 0, 0);
}

// ---------------- K1: key norms + normalized bf16 conversion ----------------
__global__ __launch_bounds__(256) void knorm_scale_kernel(const float* __restrict__ keys,
                                                          unsigned short* __restrict__ kb,
                                                          float* __restrict__ rnk) {
  int row = blockIdx.x;
  int tid = threadIdx.x;
  float4 v = reinterpret_cast<const float4*>(keys + (size_t)row * D_N)[tid];
  float s = v.x * v.x + v.y * v.y + v.z * v.z + v.w * v.w;
#pragma unroll
  for (int off = 32; off > 0; off >>= 1) s += __shfl_down(s, off);
  __shared__ float part[4];
  __shared__ float rs;
  int lane = tid & 63, wid = tid >> 6;
  if (lane == 0) part[wid] = s;
  __syncthreads();
  if (tid == 0) {
    float t = part[0] + part[1] + part[2] + part[3];
    rs = 1.0f / fmaxf(sqrtf(t), 1e-12f);
  }
  __syncthreads();
  float r = rs;
  ushort4 o;
  o.x = f2bf(v.x * r); o.y = f2bf(v.y * r); o.z = f2bf(v.z * r); o.w = f2bf(v.w * r);
  reinterpret_cast<ushort4*>(kb + (size_t)row * D_N)[tid] = o;
  if (tid == 0) rnk[row] = r;
}

// ---------------- K2: query norms -> fp32 (rescore) + bf16 (MFMA) ----------
__global__ __launch_bounds__(256) void qnorm_dual_kernel(const float* __restrict__ q,
                                                         float* __restrict__ qn,
                                                         unsigned short* __restrict__ qb) {
  int row = blockIdx.x;
  int tid = threadIdx.x;
  float4 v = reinterpret_cast<const float4*>(q + (size_t)row * D_N)[tid];
  float s = v.x * v.x + v.y * v.y + v.z * v.z + v.w * v.w;
#pragma unroll
  for (int off = 32; off > 0; off >>= 1) s += __shfl_down(s, off);
  __shared__ float part[4];
  __shared__ float rs;
  int lane = tid & 63, wid = tid >> 6;
  if (lane == 0) part[wid] = s;
  __syncthreads();
  if (tid == 0) {
    float t = part[0] + part[1] + part[2] + part[3];
    rs = 1.0f / fmaxf(sqrtf(t), 1e-12f);
  }
  __syncthreads();
  float r = rs;
  float4 o;
  o.x = v.x * r; o.y = v.y * r; o.z = v.z * r; o.w = v.w * r;
  reinterpret_cast<float4*>(qn + (size_t)row * D_N)[tid] = o;
  ushort4 ob;
  ob.x = f2bf(o.x); ob.y = f2bf(o.y); ob.z = f2bf(o.z); ob.w = f2bf(o.w);
  reinterpret_cast<ushort4*>(qb + (size_t)row * D_N)[tid] = ob;
}

// ---------------- K3: bf16 MFMA sims + in-register per-segment top-8 --------
// R14 instruction-diet kernel (compile-time slots -> ds_read imm offsets,
// incremental staging pointers, screened fold) moved to RING-3 (48 KB LDS,
// 3 blocks/CU), unroll-3 over 510 steps + 2-step epilogue, 2-step prefetch
// lookahead, counted vmcnt(4). Single raw barrier/step (R10-validated ring
// logic), R11 cache-partitioned mapping, swapped-operand 16x16x32 MFMA.
__global__ __launch_bounds__(256, 3) void simsb_kernel(const unsigned short* __restrict__ qb,
                                                       const unsigned short* __restrict__ kb,
                                                       float* __restrict__ cand_val,
                                                       int* __restrict__ cand_idx) {
  __shared__ __align__(16) union SmemU {
    struct {
      unsigned short A[3][BM * BK];  // 3 x 8 KB queries
      unsigned short B[3][BN * BK];  // 3 x 8 KB keys
    } ab;                            // 48 KB
    struct {
      float v[BM * 4 * TOPK];        // 16 KB
      int i[BM * 4 * TOPK];          // 16 KB
    } mg;
  } smem;

  const int tid = threadIdx.x;
  const int lane = tid & 63;
  const int wid = tid >> 6;

  // R11 cache-partitioned mapping: x = XCD, idx in-XCD.
  const int orig = blockIdx.x;
  const int x = orig & 7;
  const int idx = orig >> 3;
  const int qtile = ((x >> 1) << 3) + (idx & 7);
  const int seg = ((x & 1) << 4) + (idx >> 3);
  const int qbase = qtile * BM;
  const int segBase = seg * KPS;

  // staging geometry (R5/R11): wave wid stages tile rows [wid*32, wid*32+32)
  // involutive chunk swizzle applied on global source; LDS dest linear
  const int srow = (wid << 5) + (lane >> 2);
  const int scol = (((lane & 3) ^ ((lane >> 3) & 3)) << 3);
  const unsigned short* aSeg = qb + (size_t)(qbase + srow) * D_N + scol;
  const unsigned short* bSeg = kb + (size_t)(segBase + srow) * D_N + scol;

  // fragment geometry (R5/R11): fr = row-within-16, g = k-chunk group
  const int fr = lane & 15;
  const int g = lane >> 4;
  const int chunk_phys = g ^ ((fr >> 1) & 3);
  // loop-invariant per-lane LDS read bases (slot offset folds into ds_read imm)
  const unsigned short* rB = &smem.ab.B[0][0] + (fr << 5) + (chunk_phys << 3);
  const unsigned short* rA = &smem.ab.A[0][0] + (((wid << 5) + fr) << 5) + (chunk_phys << 3);

  // per-lane running top-8 for 2 queries (q = qbase + wid*32 + n*16 + fr),
  // over this lane's key partition (keys m*16 + g*4 + j)
  float lv[2][TOPK];
  int li[2][TOPK];
#pragma unroll
  for (int n = 0; n < 2; ++n)
#pragma unroll
    for (int j = 0; j < TOPK; ++j) { lv[n][j] = -1e30f; li[n][j] = 0x7fffffff; }

  f32x4 acc[8][2];
#pragma unroll
  for (int m = 0; m < 8; ++m)
#pragma unroll
    for (int n = 0; n < 2; ++n) acc[m][n] = (f32x4)0.0f;

  // prologue: stage steps 0,1 into slots 0,1 (8 loads in flight per wave)
#pragma unroll
  for (int p = 0; p < 2; ++p) {
    const unsigned short* aS = aSeg + (p << 5);
    const unsigned short* bS = bSeg + (p << 5);
    unsigned short* Ad = &smem.ab.A[p][0] + (wid << 10);
    unsigned short* Bd = &smem.ab.B[p][0] + (wid << 10);
    gll16(Ad, aS);
    gll16(Ad + 512, aS + (size_t)16 * D_N);
    gll16(Bd, bS);
    gll16(Bd + 512, bS + (size_t)16 * D_N);
  }

  // incremental restage pointers, positioned at target step 2 (offset 64 ush)
  const unsigned short* aP0 = aSeg + 64;
  const unsigned short* aP1 = aP0 + (size_t)16 * D_N;
  const unsigned short* bP0 = bSeg + 64;
  const unsigned short* bP1 = bP0 + (size_t)16 * D_N;

#define SWAIT_(N) asm volatile("s_waitcnt vmcnt(" #N ")" ::: "memory")
#define SWAIT(N) SWAIT_(N)

#define FOLD(V)                                                               \
  {                                                                           \
    const int kb0 = segBase + (((V) >> 5) << 7) + (g << 2);                   \
    _Pragma("unroll")                                                         \
    for (int n = 0; n < 2; ++n)                                               \
      _Pragma("unroll")                                                       \
      for (int m = 0; m < 8; ++m) {                                           \
        float q0 = acc[m][n][0], q1 = acc[m][n][1];                           \
        float q2 = acc[m][n][2], q3 = acc[m][n][3];                           \
        acc[m][n] = (f32x4)0.0f;                                              \
        float mx = fmaxf(fmaxf(q0, q1), fmaxf(q2, q3));                       \
        const int id0 = kb0 + (m << 4);                                       \
        if (better(mx, id0, lv[n][TOPK - 1], li[n][TOPK - 1])) {              \
          float vals[4] = {q0, q1, q2, q3};                                   \
          _Pragma("unroll")                                                   \
          for (int j = 0; j < 4; ++j) {                                       \
            float val = vals[j];                                              \
            int id = id0 + j;                                                 \
            if (better(val, id, lv[n][TOPK - 1], li[n][TOPK - 1])) {          \
              float cv = val; int ci = id;                                    \
              _Pragma("unroll")                                               \
              for (int p = 0; p < TOPK; ++p) {                                \
                if (better(cv, ci, lv[n][p], li[n][p])) {                     \
                  float tv = lv[n][p]; int ti = li[n][p];                     \
                  lv[n][p] = cv; li[n][p] = ci;                               \
                  cv = tv; ci = ti;                                           \
                }                                                             \
              }                                                               \
            }                                                                 \
          }                                                                   \
        }                                                                     \
      }                                                                       \
  }

  // STEP: SLOT compile-time (0..2); restage target slot (SLOT+2)%3 was last
  // read at step V-1 (readers done: their MFMAs consumed the reads, and the
  // MFMAs precede this step's barrier in their program order).
#define STEP(V, SLOT, WAITN, RESTAGE)                                         \
  {                                                                           \
    SWAIT(WAITN);                                                             \
    __builtin_amdgcn_sched_barrier(0);                                        \
    __builtin_amdgcn_s_barrier();                                             \
    __builtin_amdgcn_sched_barrier(0);                                        \
    if (RESTAGE) {                                                            \
      unsigned short* Ad = &smem.ab.A[((SLOT) + 2) % 3][0] + (wid << 10);     \
      unsigned short* Bd = &smem.ab.B[((SLOT) + 2) % 3][0] + (wid << 10);     \
      gll16(Ad, aP0);                                                         \
      gll16(Ad + 512, aP1);                                                   \
      gll16(Bd, bP0);                                                         \
      gll16(Bd + 512, bP1);                                                   \
    }                                                                         \
    {                                                                         \
      const bool wrp = (((V) & 31) == 29);                                    \
      const int dA = wrp ? -992 : 32;                                         \
      const int dB = wrp ? 130080 : 32;                                       \
      aP0 += dA; aP1 += dA; bP0 += dB; bP1 += dB;                             \
    }                                                                         \
    s16x8 af[8], bq[2];                                                       \
    _Pragma("unroll")                                                         \
    for (int m = 0; m < 8; ++m)                                               \
      af[m] = *(const s16x8*)(rB + (SLOT) * 4096 + (m << 9));                 \
    bq[0] = *(const s16x8*)(rA + (SLOT) * 4096);                              \
    bq[1] = *(const s16x8*)(rA + (SLOT) * 4096 + 512);                        \
    __builtin_amdgcn_s_setprio(1);                                            \
    _Pragma("unroll")                                                         \
    for (int m = 0; m < 8; ++m) {                                             \
      acc[m][0] = __builtin_amdgcn_mfma_f32_16x16x32_bf16(af[m], bq[0], acc[m][0], 0, 0, 0); \
      acc[m][1] = __builtin_amdgcn_mfma_f32_16x16x32_bf16(af[m], bq[1], acc[m][1], 0, 0, 0); \
    }                                                                         \
    __builtin_amdgcn_s_setprio(0);                                            \
    if (((V) & 31) == 31) FOLD(V)                                             \
  }

#pragma unroll 1
  for (int vb = 0; vb < NSTEP - 2; vb += 3) {   // 510 steps in-loop
    STEP(vb + 0, 0, 4, 1)
    STEP(vb + 1, 1, 4, 1)
    STEP(vb + 2, 2, 4, 1)
  }
  // epilogue: v = 510, 511 (509 already restaged 511; then drain)
  STEP(510, 0, 4, 0)
  STEP(511, 1, 0, 0)
#undef STEP
#undef FOLD
#undef SWAIT
#undef SWAIT_

  __syncthreads();   // all LDS frag reads done before overlaying mg scratch

  // dump per-lane lists: query-local ql = wid*32 + n*16 + fr, group g
#pragma unroll
  for (int n = 0; n < 2; ++n) {
    const int ql = (wid << 5) + (n << 4) + fr;
#pragma unroll
    for (int j = 0; j < TOPK; ++j) {
      smem.mg.v[((ql << 2) + g) * TOPK + j] = lv[n][j];
      smem.mg.i[((ql << 2) + g) * TOPK + j] = li[n][j];
    }
  }
  __syncthreads();

  // thread per query: 4-way merge of the 4 sorted lane-group lists -> top-8
  if (tid < BM) {
    const int rb = tid << 5;   // 4 lists x 8
    int p0 = 0, p1 = 0, p2 = 0, p3 = 0;
    size_t base = (size_t)(qbase + tid) * CANDS + seg * TOPK;
#pragma unroll
    for (int j = 0; j < TOPK; ++j) {
      float v0 = smem.mg.v[rb + 0 + p0];  int i0 = smem.mg.i[rb + 0 + p0];
      float v1 = smem.mg.v[rb + 8 + p1];  int i1 = smem.mg.i[rb + 8 + p1];
      float v2 = smem.mg.v[rb + 16 + p2]; int i2 = smem.mg.i[rb + 16 + p2];
      float v3 = smem.mg.v[rb + 24 + p3]; int i3 = smem.mg.i[rb + 24 + p3];
      float bv = v0; int bi = i0; int sel = 0;
      if (better(v1, i1, bv, bi)) { bv = v1; bi = i1; sel = 1; }
      if (better(v2, i2, bv, bi)) { bv = v2; bi = i2; sel = 2; }
      if (better(v3, i3, bv, bi)) { bv = v3; bi = i3; sel = 3; }
      cand_val[base + j] = bv;
      cand_idx[base + j] = bi;
      p0 += (sel == 0); p1 += (sel == 1); p2 += (sel == 2); p3 += (sel == 3);
    }
  }
}

// ---------------- K4: merge + exact fp32 rescore + select + gather ---------
__global__ __launch_bounds__(256) void merge_kernel(const float* __restrict__ qn,
                                                    const float* __restrict__ keys,
                                                    const float* __restrict__ values,
                                                    const float* __restrict__ rnk,
                                                    const float* __restrict__ cand_val,
                                                    const int* __restrict__ cand_idx,
                                                    float* __restrict__ out) {
  const int q = blockIdx.x;
  const int tid = threadIdx.x;
  const int lane = tid & 63;
  const int w = tid >> 6;
  __shared__ float sv[CANDS];
  __shared__ int si[CANDS];
  sv[tid] = cand_val[(size_t)q * CANDS + tid];
  si[tid] = cand_idx[(size_t)q * CANDS + tid];
  __syncthreads();
  for (int k = 2; k <= CANDS; k <<= 1) {
    for (int j = k >> 1; j > 0; j >>= 1) {
      int ixj = tid ^ j;
      if (ixj > tid) {
        float v0 = sv[tid], v1 = sv[ixj];
        int i0 = si[tid], i1 = si[ixj];
        bool desc = ((tid & k) == 0);
        bool dosw = desc ? better(v1, i1, v0, i0) : better(v0, i0, v1, i1);
        if (dosw) { sv[tid] = v1; si[tid] = i1; sv[ixj] = v0; si[ixj] = i0; }
      }
      __syncthreads();
    }
  }
  __shared__ float rsc[NRES];
  const float* qrow = &qn[(size_t)q * D_N + lane * 16];
  float4 qv0 = *reinterpret_cast<const float4*>(qrow + 0);
  float4 qv1 = *reinterpret_cast<const float4*>(qrow + 4);
  float4 qv2 = *reinterpret_cast<const float4*>(qrow + 8);
  float4 qv3 = *reinterpret_cast<const float4*>(qrow + 12);
  for (int c = w; c < NRES; c += 4) {
    int id = si[c];
    const float* kr = &keys[(size_t)id * D_N + lane * 16];
    float4 k0 = *reinterpret_cast<const float4*>(kr + 0);
    float4 k1 = *reinterpret_cast<const float4*>(kr + 4);
    float4 k2 = *reinterpret_cast<const float4*>(kr + 8);
    float4 k3 = *reinterpret_cast<const float4*>(kr + 12);
    float s = qv0.x * k0.x + qv0.y * k0.y + qv0.z * k0.z + qv0.w * k0.w
            + qv1.x * k1.x + qv1.y * k1.y + qv1.z * k1.z + qv1.w * k1.w
            + qv2.x * k2.x + qv2.y * k2.y + qv2.z * k2.z + qv2.w * k2.w
            + qv3.x * k3.x + qv3.y * k3.y + qv3.z * k3.z + qv3.w * k3.w;
#pragma unroll
    for (int off = 32; off > 0; off >>= 1) s += __shfl_down(s, off);
    if (lane == 0) rsc[c] = s * rnk[id];
  }
  __syncthreads();
  __shared__ int sel[TOPK];
  if (tid == 0) {
    unsigned used = 0;
    for (int j = 0; j < TOPK; ++j) {
      int best = -1;
      for (int c = 0; c < NRES; ++c) {
        if ((used >> c) & 1u) continue;
        if (best < 0 || better(rsc[c], si[c], rsc[best], si[best])) best = c;
      }
      used |= 1u << best;
      sel[j] = si[best];
    }
  }
  __syncthreads();
#pragma unroll
  for (int j = 0; j < TOPK; ++j) {
    int row = sel[j];
    float4 v = *reinterpret_cast<const float4*>(&values[(size_t)row * D_N + tid * 4]);
    *reinterpret_cast<float4*>(&out[(size_t)q * (TOPK * D_N) + j * D_N + tid * 4]) = v;
  }
}

extern "C" void kernel_launch(void* const* d_in, const int* in_sizes, int n_in,
                              void* d_out, int out_size, void* d_ws, size_t ws_size,
                              hipStream_t stream) {
  const float* query  = (const float*)d_in[0];
  const float* keys   = (const float*)d_in[1];
  const float* values = (const float*)d_in[2];
  float* out = (float*)d_out;
  char* ws = (char*)d_ws;

  const size_t offQn  = 0;
  const size_t offQb  = offQn + (size_t)Q_N * D_N * 4;
  const size_t offKb  = offQb + (size_t)Q_N * D_N * 2;
  const size_t offRnk = offKb + (size_t)M_N * D_N * 2;
  const size_t offCv  = offRnk + (size_t)M_N * 4;
  const size_t offCi  = offCv + (size_t)Q_N * CANDS * 4;

  float* qn = (float*)(ws + offQn);
  unsigned short* qb = (unsigned short*)(ws + offQb);
  unsigned short* kb = (unsigned short*)(ws + offKb);
  float* rnk = (float*)(ws + offRnk);
  float* cand_val = (float*)(ws + offCv);
  int* cand_idx = (int*)(ws + offCi);

  hipLaunchKernelGGL(knorm_scale_kernel, dim3(M_N), dim3(256), 0, stream, keys, kb, rnk);
  hipLaunchKernelGGL(qnorm_dual_kernel, dim3(Q_N), dim3(256), 0, stream, query, qn, qb);
  hipLaunchKernelGGL(simsb_kernel, dim3(QT128 * SEGS), dim3(256), 0, stream,
                     qb, kb, cand_val, cand_idx);
  hipLaunchKernelGGL(merge_kernel, dim3(Q_N), dim3(256), 0, stream,
                     qn, keys, values, rnk, cand_val, cand_idx, out);
}